// Round 2
// baseline (175.391 us; speedup 1.0000x reference)
//
#include <hip/hip_runtime.h>

#define INV_SQRT2 0.70710678118654752440f

// Original (non-reversed) analysis filter tables, exactly as in the reference.
// The synthesis filters are the time-reversed rows; we fold the reversal into
// the index:  out[2s+r] = sum_p ORIG[9 - r - 2p][ch] * x[(s+2-p) mod n]
__constant__ float c_first[2][10][2] = {
  { { 0.00000000000000f,  0.00000000000000f},
    {-0.08838834764832f, -0.01122679215254f},
    { 0.08838834764832f,  0.01122679215254f},
    { 0.69587998903400f,  0.08838834764832f},
    { 0.69587998903400f,  0.08838834764832f},
    { 0.08838834764832f, -0.69587998903400f},
    {-0.08838834764832f,  0.69587998903400f},
    { 0.01122679215254f, -0.08838834764832f},
    { 0.01122679215254f, -0.08838834764832f},
    { 0.00000000000000f,  0.00000000000000f} },
  { { 0.01122679215254f,  0.00000000000000f},
    { 0.01122679215254f,  0.00000000000000f},
    {-0.08838834764832f, -0.08838834764832f},
    { 0.08838834764832f, -0.08838834764832f},
    { 0.69587998903400f,  0.69587998903400f},
    { 0.69587998903400f, -0.69587998903400f},
    { 0.08838834764832f,  0.08838834764832f},
    {-0.08838834764832f,  0.08838834764832f},
    { 0.00000000000000f,  0.01122679215254f},
    { 0.00000000000000f, -0.01122679215254f} }
};

__constant__ float c_qshift[2][10][2] = {
  { { 0.03516384f,  0.00000000f},
    { 0.00000000f,  0.00000000f},
    {-0.08832942f, -0.11430184f},
    { 0.23389032f,  0.00000000f},
    { 0.76027237f,  0.58751830f},
    { 0.58751830f, -0.76027237f},
    { 0.00000000f,  0.23389032f},
    {-0.11430184f,  0.08832942f},
    { 0.00000000f,  0.00000000f},
    { 0.00000000f, -0.03516384f} },
  { { 0.00000000f, -0.03516384f},
    { 0.00000000f,  0.00000000f},
    {-0.11430184f,  0.08832942f},
    { 0.00000000f,  0.23389032f},
    { 0.58751830f, -0.76027237f},
    { 0.76027237f,  0.58751830f},
    { 0.23389032f,  0.00000000f},
    {-0.08832942f, -0.11430184f},
    { 0.00000000f,  0.00000000f},
    { 0.03516384f,  0.00000000f} }
};

// ---------------------------------------------------------------------------
// Stage 1: level-2 synthesis (Q-shift). For combo = m*2+n:
//   lo2[combo] = sfb2d(lows[m,n], butterflied(highs1), SF[m] rows, SF[n] cols)
// One thread owns (combo,b, column t, channel c, row segment), computes BOTH
// column parities (shared taps), streams rows with a 5-deep register window.
// SEG=8 s-values per thread (12 iters incl. 4-row halo prologue): grid sized
// for 75% wave-slot occupancy (was 37.5% at SEG=16 -> latency-bound).
// ---------------------------------------------------------------------------
__global__ __launch_bounds__(128) void idtcwt_stage1(
    const float* __restrict__ lows, const float* __restrict__ highs1,
    float* __restrict__ lo2)
{
  constexpr int HIN = 128, WIN = 128, C = 3, B = 16;
  constexpr int ROWF  = WIN * C;        // 384 floats per input row
  constexpr int ROWO  = 2 * WIN * C;    // 768 floats per output row
  constexpr int PLANE = HIN * WIN * C;  // 49152
  constexpr int SEG   = 8;

  const int jj = blockIdx.x * 128 + threadIdx.x;  // 0..383 = (t, c)
  const int c  = jj % 3;
  const int t  = jj / 3;                // input column 0..127
  const int z  = blockIdx.z;            // combo*16 + b
  const int combo = z >> 4;
  const int b     = z & 15;
  const int m = combo >> 1, n = combo & 1;

  const float* lo = lows + (combo * B + b) * PLANE;
  // butterfly tree pair: m==n -> trees (0,0)&(1,1); else (0,1)&(1,0); sign by m
  const int pa = (m == n) ? 0 : 1;
  const int pb = (m == n) ? 3 : 2;
  const float sgn = (m == 0) ? 1.0f : -1.0f;
  const int bandStride = B * PLANE;     // 786432
  const float* hA = highs1 + (pa * 3 * B + b) * PLANE;  // band 0 base
  const float* hB = highs1 + (pb * 3 * B + b) * PLANE;

  int wc3[5];
#pragma unroll
  for (int p = 0; p < 5; ++p) {
    int w = t + 2 - p;
    if (w >= WIN) w -= WIN;
    if (w < 0)  w += WIN;
    wc3[p] = w * C + c;
  }

  float lae[5], lao[5], hae[5], hao[5];
#pragma unroll
  for (int k = 0; k < 5; ++k) { lae[k]=0.f; lao[k]=0.f; hae[k]=0.f; hao[k]=0.f; }

  const int s0 = blockIdx.y * SEG;
  float* outp = lo2 + (combo * B + b) * (4 * PLANE);  // 256*256*3 per plane

#pragma unroll 1
  for (int ui = 0; ui < SEG + 4; ++ui) {
    const int u  = (s0 - 2 + ui) & (HIN - 1);
    // slide window
#pragma unroll
    for (int k = 0; k < 4; ++k) { lae[k]=lae[k+1]; lao[k]=lao[k+1]; hae[k]=hae[k+1]; hao[k]=hao[k+1]; }
    const int rb = u * ROWF;
    float aLe=0.f, aLo=0.f, aHe=0.f, aHo=0.f;
#pragma unroll
    for (int p = 0; p < 5; ++p) {
      const int idx = rb + wc3[p];
      const float lv  = lo[idx];
      const float lhv = (hA[idx]                + sgn * hB[idx])                * INV_SQRT2;
      const float hlv = (hA[idx +   bandStride] + sgn * hB[idx +   bandStride]) * INV_SQRT2;
      const float hhv = (hA[idx + 2*bandStride] + sgn * hB[idx + 2*bandStride]) * INV_SQRT2;
      const float ce0 = c_qshift[n][9 - 2*p][0], ce1 = c_qshift[n][9 - 2*p][1];
      const float co0 = c_qshift[n][8 - 2*p][0], co1 = c_qshift[n][8 - 2*p][1];
      aLe += ce0 * lv  + ce1 * lhv;
      aLo += co0 * lv  + co1 * lhv;
      aHe += ce0 * hlv + ce1 * hhv;
      aHo += co0 * hlv + co1 * hhv;
    }
    lae[4]=aLe; lao[4]=aLo; hae[4]=aHe; hao[4]=aHo;

    if (ui >= 4) {
      const int s = s0 + ui - 4;
      float o00=0.f, o01=0.f, o10=0.f, o11=0.f;   // o{row parity}{col parity}
#pragma unroll
      for (int p = 0; p < 5; ++p) {
        const float f0l = c_qshift[m][9 - 2*p][0], f0h = c_qshift[m][9 - 2*p][1];
        const float f1l = c_qshift[m][8 - 2*p][0], f1h = c_qshift[m][8 - 2*p][1];
        o00 += f0l*lae[4-p] + f0h*hae[4-p];
        o01 += f0l*lao[4-p] + f0h*hao[4-p];
        o10 += f1l*lae[4-p] + f1h*hae[4-p];
        o11 += f1l*lao[4-p] + f1h*hao[4-p];
      }
      float* q = outp + (2*s) * ROWO + (2*t) * C + c;
      q[0]        = o00;
      q[C]        = o01;
      q[ROWO]     = o10;
      q[ROWO + C] = o11;
    }
  }
}

// ---------------------------------------------------------------------------
// Stage 2: level-1 synthesis (first-stage filters), all 4 combos fused.
// Row filter depends only on m, so we pre-sum the column-pass results over n:
//   LA_m(u) = sum_n colpass_n(lo2[m][n], LH_{m,n}),  HA_m analogous.
// Output y is written exactly once, scaled by 1/2. SEG=8 (was 16): doubles
// wave count -> occupancy cap 37.5% -> 75%.
// ---------------------------------------------------------------------------
__global__ __launch_bounds__(256) void idtcwt_stage2(
    const float* __restrict__ lo2, const float* __restrict__ highs0,
    float* __restrict__ out)
{
  constexpr int HIN = 256, WIN = 256, C = 3, B = 16;
  constexpr int ROWF  = WIN * C;        // 768
  constexpr int ROWO  = 2 * WIN * C;    // 1536
  constexpr int PLANE = HIN * WIN * C;  // 196608
  constexpr int OPLANE = 512 * 512 * C; // 786432
  constexpr int SEG   = 8;

  const int jj = blockIdx.x * 256 + threadIdx.x;  // 0..767 = (t, c)
  const int c  = jj % 3;
  const int t  = jj / 3;               // 0..255
  const int b  = blockIdx.z;

  const float* l00 = lo2 + (0 * B + b) * PLANE;   // combo (0,0)
  const float* l01 = lo2 + (1 * B + b) * PLANE;   // (0,1)
  const float* l10 = lo2 + (2 * B + b) * PLANE;   // (1,0)
  const float* l11 = lo2 + (3 * B + b) * PLANE;   // (1,1)
  const int bandStride = B * PLANE;               // 3145728
  const float* h00 = highs0 + (0 * 3 * B + b) * PLANE;  // tree (0,0), band 0
  const float* h01 = highs0 + (1 * 3 * B + b) * PLANE;
  const float* h10 = highs0 + (2 * 3 * B + b) * PLANE;
  const float* h11 = highs0 + (3 * 3 * B + b) * PLANE;

  int wc3[5];
#pragma unroll
  for (int p = 0; p < 5; ++p) {
    int w = t + 2 - p;
    if (w >= WIN) w -= WIN;
    if (w < 0)  w += WIN;
    wc3[p] = w * C + c;
  }

  float la0e[5], la0o[5], la1e[5], la1o[5];
  float ha0e[5], ha0o[5], ha1e[5], ha1o[5];
#pragma unroll
  for (int k = 0; k < 5; ++k) {
    la0e[k]=0.f; la0o[k]=0.f; la1e[k]=0.f; la1o[k]=0.f;
    ha0e[k]=0.f; ha0o[k]=0.f; ha1e[k]=0.f; ha1o[k]=0.f;
  }

  const int s0 = blockIdx.y * SEG;
  float* outb = out + b * OPLANE;

#pragma unroll 1
  for (int ui = 0; ui < SEG + 4; ++ui) {
    const int u  = (s0 - 2 + ui) & (HIN - 1);
#pragma unroll
    for (int k = 0; k < 4; ++k) {
      la0e[k]=la0e[k+1]; la0o[k]=la0o[k+1]; la1e[k]=la1e[k+1]; la1o[k]=la1o[k+1];
      ha0e[k]=ha0e[k+1]; ha0o[k]=ha0o[k+1]; ha1e[k]=ha1e[k+1]; ha1o[k]=ha1o[k+1];
    }
    const int rb = u * ROWF;
    float A0e=0.f,A0o=0.f,A1e=0.f,A1o=0.f, H0e=0.f,H0o=0.f,H1e=0.f,H1o=0.f;
#pragma unroll
    for (int p = 0; p < 5; ++p) {
      const int idx = rb + wc3[p];
      const float a0e = c_first[0][9-2*p][0], a0o = c_first[0][8-2*p][0];
      const float b0e = c_first[0][9-2*p][1], b0o = c_first[0][8-2*p][1];
      const float a1e = c_first[1][9-2*p][0], a1o = c_first[1][8-2*p][0];
      const float b1e = c_first[1][9-2*p][1], b1o = c_first[1][8-2*p][1];
      { // lo2 terms: filter-n ch0, no butterfly
        const float v00=l00[idx], v01=l01[idx], v10=l10[idx], v11=l11[idx];
        A0e += a0e*v00 + a1e*v01;   A0o += a0o*v00 + a1o*v01;
        A1e += a0e*v10 + a1e*v11;   A1o += a0o*v10 + a1o*v11;
      }
      { // LH band (ch1 coeff)
        const float x00=h00[idx], x11=h11[idx], x01=h01[idx], x10=h10[idx];
        const float s1=(x00+x11)*INV_SQRT2, d1=(x00-x11)*INV_SQRT2;
        const float s2=(x01+x10)*INV_SQRT2, d2=(x01-x10)*INV_SQRT2;
        A0e += b0e*s1 + b1e*s2;   A0o += b0o*s1 + b1o*s2;
        A1e += b0e*d2 + b1e*d1;   A1o += b0o*d2 + b1o*d1;
      }
      { // HL band (ch0 coeff)
        const int i1 = idx + bandStride;
        const float x00=h00[i1], x11=h11[i1], x01=h01[i1], x10=h10[i1];
        const float s1=(x00+x11)*INV_SQRT2, d1=(x00-x11)*INV_SQRT2;
        const float s2=(x01+x10)*INV_SQRT2, d2=(x01-x10)*INV_SQRT2;
        H0e += a0e*s1 + a1e*s2;   H0o += a0o*s1 + a1o*s2;
        H1e += a0e*d2 + a1e*d1;   H1o += a0o*d2 + a1o*d1;
      }
      { // HH band (ch1 coeff)
        const int i2 = idx + 2*bandStride;
        const float x00=h00[i2], x11=h11[i2], x01=h01[i2], x10=h10[i2];
        const float s1=(x00+x11)*INV_SQRT2, d1=(x00-x11)*INV_SQRT2;
        const float s2=(x01+x10)*INV_SQRT2, d2=(x01-x10)*INV_SQRT2;
        H0e += b0e*s1 + b1e*s2;   H0o += b0o*s1 + b1o*s2;
        H1e += b0e*d2 + b1e*d1;   H1o += b0o*d2 + b1o*d1;
      }
    }
    la0e[4]=A0e; la0o[4]=A0o; la1e[4]=A1e; la1o[4]=A1o;
    ha0e[4]=H0e; ha0o[4]=H0o; ha1e[4]=H1e; ha1o[4]=H1o;

    if (ui >= 4) {
      const int s = s0 + ui - 4;
      float o00=0.f, o01=0.f, o10=0.f, o11=0.f;   // o{row parity}{col parity}
#pragma unroll
      for (int p = 0; p < 5; ++p) {
        const float f00 = c_first[0][9-2*p][0], g00 = c_first[0][9-2*p][1]; // m=0, r=0
        const float f01 = c_first[0][8-2*p][0], g01 = c_first[0][8-2*p][1]; // m=0, r=1
        const float f10 = c_first[1][9-2*p][0], g10 = c_first[1][9-2*p][1]; // m=1, r=0
        const float f11 = c_first[1][8-2*p][0], g11 = c_first[1][8-2*p][1]; // m=1, r=1
        o00 += f00*la0e[4-p] + g00*ha0e[4-p] + f10*la1e[4-p] + g10*ha1e[4-p];
        o01 += f00*la0o[4-p] + g00*ha0o[4-p] + f10*la1o[4-p] + g10*ha1o[4-p];
        o10 += f01*la0e[4-p] + g01*ha0e[4-p] + f11*la1e[4-p] + g11*ha1e[4-p];
        o11 += f01*la0o[4-p] + g01*ha0o[4-p] + f11*la1o[4-p] + g11*ha1o[4-p];
      }
      float* q = outb + (2*s) * ROWO + (2*t) * C + c;
      q[0]        = o00 * 0.5f;
      q[C]        = o01 * 0.5f;
      q[ROWO]     = o10 * 0.5f;
      q[ROWO + C] = o11 * 0.5f;
    }
  }
}

extern "C" void kernel_launch(void* const* d_in, const int* in_sizes, int n_in,
                              void* d_out, int out_size, void* d_ws, size_t ws_size,
                              hipStream_t stream) {
  const float* highs0 = (const float*)d_in[0];  // (2,2,3,16,256,256,3)
  const float* highs1 = (const float*)d_in[1];  // (2,2,3,16,128,128,3)
  const float* lows   = (const float*)d_in[2];  // (2,2,16,128,128,3)
  float* out = (float*)d_out;                   // (16,512,512,3)
  float* lo2 = (float*)d_ws;                    // 4*16*256*256*3 floats = 50.3 MB

  // Stage 1: 384 cols/plane -> 3 blocks of 128; 16 row segments of 8; 4x16 planes
  dim3 b1(128), g1(3, 16, 64);
  hipLaunchKernelGGL(idtcwt_stage1, g1, b1, 0, stream, lows, highs1, lo2);

  // Stage 2: 768 cols -> 3 blocks of 256; 32 row segments of 8; 16 batches
  dim3 b2(256), g2(3, 32, 16);
  hipLaunchKernelGGL(idtcwt_stage2, g2, b2, 0, stream, lo2, highs0, out);
}

// Round 3
// 146.107 us; speedup vs baseline: 1.2004x; 1.2004x over previous
//
#include <hip/hip_runtime.h>

#define INV_SQRT2 0.70710678118654752440f

// Original (non-reversed) analysis filter tables, exactly as in the reference.
// The synthesis filters are the time-reversed rows; we fold the reversal into
// the index:  out[2s+r] = sum_p ORIG[9 - r - 2p][ch] * x[(s+2-p) mod n]
__constant__ float c_first[2][10][2] = {
  { { 0.00000000000000f,  0.00000000000000f},
    {-0.08838834764832f, -0.01122679215254f},
    { 0.08838834764832f,  0.01122679215254f},
    { 0.69587998903400f,  0.08838834764832f},
    { 0.69587998903400f,  0.08838834764832f},
    { 0.08838834764832f, -0.69587998903400f},
    {-0.08838834764832f,  0.69587998903400f},
    { 0.01122679215254f, -0.08838834764832f},
    { 0.01122679215254f, -0.08838834764832f},
    { 0.00000000000000f,  0.00000000000000f} },
  { { 0.01122679215254f,  0.00000000000000f},
    { 0.01122679215254f,  0.00000000000000f},
    {-0.08838834764832f, -0.08838834764832f},
    { 0.08838834764832f, -0.08838834764832f},
    { 0.69587998903400f,  0.69587998903400f},
    { 0.69587998903400f, -0.69587998903400f},
    { 0.08838834764832f,  0.08838834764832f},
    {-0.08838834764832f,  0.08838834764832f},
    { 0.00000000000000f,  0.01122679215254f},
    { 0.00000000000000f, -0.01122679215254f} }
};

__constant__ float c_qshift[2][10][2] = {
  { { 0.03516384f,  0.00000000f},
    { 0.00000000f,  0.00000000f},
    {-0.08832942f, -0.11430184f},
    { 0.23389032f,  0.00000000f},
    { 0.76027237f,  0.58751830f},
    { 0.58751830f, -0.76027237f},
    { 0.00000000f,  0.23389032f},
    {-0.11430184f,  0.08832942f},
    { 0.00000000f,  0.00000000f},
    { 0.00000000f, -0.03516384f} },
  { { 0.00000000f, -0.03516384f},
    { 0.00000000f,  0.00000000f},
    {-0.11430184f,  0.08832942f},
    { 0.00000000f,  0.23389032f},
    { 0.58751830f, -0.76027237f},
    { 0.76027237f,  0.58751830f},
    { 0.23389032f,  0.00000000f},
    {-0.08832942f, -0.11430184f},
    { 0.00000000f,  0.00000000f},
    { 0.03516384f,  0.00000000f} }
};

// ---------------------------------------------------------------------------
// Stage 1: level-2 synthesis (Q-shift). For combo = m*2+n:
//   lo2[combo] = sfb2d(lows[m,n], butterflied(highs1), SF[m] rows, SF[n] cols)
// One thread owns (combo,b, column t, channel c, row segment), computes BOTH
// column parities (shared taps), streams rows with a 5-deep register window.
// SEG=16 (R1 best). Per row: batch ALL 35 loads into static local arrays
// first (single waitcnt per row), then butterfly+FMA.
// ---------------------------------------------------------------------------
__global__ __launch_bounds__(128) void idtcwt_stage1(
    const float* __restrict__ lows, const float* __restrict__ highs1,
    float* __restrict__ lo2)
{
  constexpr int HIN = 128, WIN = 128, C = 3, B = 16;
  constexpr int ROWF  = WIN * C;        // 384 floats per input row
  constexpr int ROWO  = 2 * WIN * C;    // 768 floats per output row
  constexpr int PLANE = HIN * WIN * C;  // 49152
  constexpr int SEG   = 16;

  const int jj = blockIdx.x * 128 + threadIdx.x;  // 0..383 = (t, c)
  const int c  = jj % 3;
  const int t  = jj / 3;                // input column 0..127
  const int z  = blockIdx.z;            // combo*16 + b
  const int combo = z >> 4;
  const int b     = z & 15;
  const int m = combo >> 1, n = combo & 1;

  const float* lo = lows + (combo * B + b) * PLANE;
  // butterfly tree pair: m==n -> trees (0,0)&(1,1); else (0,1)&(1,0); sign by m
  const int pa = (m == n) ? 0 : 1;
  const int pb = (m == n) ? 3 : 2;
  const float sgn = (m == 0) ? 1.0f : -1.0f;
  const int bandStride = B * PLANE;     // 786432
  const float* hA = highs1 + (pa * 3 * B + b) * PLANE;  // band 0 base
  const float* hB = highs1 + (pb * 3 * B + b) * PLANE;

  int wc3[5];
#pragma unroll
  for (int p = 0; p < 5; ++p) {
    int w = t + 2 - p;
    if (w >= WIN) w -= WIN;
    if (w < 0)  w += WIN;
    wc3[p] = w * C + c;
  }

  float lae[5], lao[5], hae[5], hao[5];
#pragma unroll
  for (int k = 0; k < 5; ++k) { lae[k]=0.f; lao[k]=0.f; hae[k]=0.f; hao[k]=0.f; }

  const int s0 = blockIdx.y * SEG;
  float* outp = lo2 + (combo * B + b) * (4 * PLANE);  // 256*256*3 per plane

#pragma unroll 1
  for (int ui = 0; ui < SEG + 4; ++ui) {
    const int u  = (s0 - 2 + ui) & (HIN - 1);
    // slide window
#pragma unroll
    for (int k = 0; k < 4; ++k) { lae[k]=lae[k+1]; lao[k]=lao[k+1]; hae[k]=hae[k+1]; hao[k]=hao[k+1]; }
    const int rb = u * ROWF;

    // ---- batched load pass: 35 loads, all static-indexed ----
    float rl[5], rA[3][5], rB[3][5];
#pragma unroll
    for (int p = 0; p < 5; ++p) {
      const int idx = rb + wc3[p];
      rl[p]    = lo[idx];
      rA[0][p] = hA[idx];
      rB[0][p] = hB[idx];
      rA[1][p] = hA[idx +   bandStride];
      rB[1][p] = hB[idx +   bandStride];
      rA[2][p] = hA[idx + 2*bandStride];
      rB[2][p] = hB[idx + 2*bandStride];
    }

    // ---- compute pass ----
    float aLe=0.f, aLo=0.f, aHe=0.f, aHo=0.f;
#pragma unroll
    for (int p = 0; p < 5; ++p) {
      const float lv  = rl[p];
      const float lhv = (rA[0][p] + sgn * rB[0][p]) * INV_SQRT2;
      const float hlv = (rA[1][p] + sgn * rB[1][p]) * INV_SQRT2;
      const float hhv = (rA[2][p] + sgn * rB[2][p]) * INV_SQRT2;
      const float ce0 = c_qshift[n][9 - 2*p][0], ce1 = c_qshift[n][9 - 2*p][1];
      const float co0 = c_qshift[n][8 - 2*p][0], co1 = c_qshift[n][8 - 2*p][1];
      aLe += ce0 * lv  + ce1 * lhv;
      aLo += co0 * lv  + co1 * lhv;
      aHe += ce0 * hlv + ce1 * hhv;
      aHo += co0 * hlv + co1 * hhv;
    }
    lae[4]=aLe; lao[4]=aLo; hae[4]=aHe; hao[4]=aHo;

    if (ui >= 4) {
      const int s = s0 + ui - 4;
      float o00=0.f, o01=0.f, o10=0.f, o11=0.f;   // o{row parity}{col parity}
#pragma unroll
      for (int p = 0; p < 5; ++p) {
        const float f0l = c_qshift[m][9 - 2*p][0], f0h = c_qshift[m][9 - 2*p][1];
        const float f1l = c_qshift[m][8 - 2*p][0], f1h = c_qshift[m][8 - 2*p][1];
        o00 += f0l*lae[4-p] + f0h*hae[4-p];
        o01 += f0l*lao[4-p] + f0h*hao[4-p];
        o10 += f1l*lae[4-p] + f1h*hae[4-p];
        o11 += f1l*lao[4-p] + f1h*hao[4-p];
      }
      float* q = outp + (2*s) * ROWO + (2*t) * C + c;
      q[0]        = o00;
      q[C]        = o01;
      q[ROWO]     = o10;
      q[ROWO + C] = o11;
    }
  }
}

// ---------------------------------------------------------------------------
// Stage 2: level-1 synthesis (first-stage filters), all 4 combos fused.
// Row filter depends only on m, so we pre-sum the column-pass results over n:
//   LA_m(u) = sum_n colpass_n(lo2[m][n], LH_{m,n}),  HA_m analogous.
// Output y is written exactly once, scaled by 1/2. SEG=16 (R1 best; SEG=8
// regressed: +56% FETCH, no latency win). Per row: batch ALL 80 loads into
// static local arrays first, then butterfly+FMA — one waitcnt per row, ~64
// loads in flight, latency hidden under neighboring waves' compute.
// ---------------------------------------------------------------------------
__global__ __launch_bounds__(256) void idtcwt_stage2(
    const float* __restrict__ lo2, const float* __restrict__ highs0,
    float* __restrict__ out)
{
  constexpr int HIN = 256, WIN = 256, C = 3, B = 16;
  constexpr int ROWF  = WIN * C;        // 768
  constexpr int ROWO  = 2 * WIN * C;    // 1536
  constexpr int PLANE = HIN * WIN * C;  // 196608
  constexpr int OPLANE = 512 * 512 * C; // 786432
  constexpr int SEG   = 16;

  const int jj = blockIdx.x * 256 + threadIdx.x;  // 0..767 = (t, c)
  const int c  = jj % 3;
  const int t  = jj / 3;               // 0..255
  const int b  = blockIdx.z;

  const float* l00 = lo2 + (0 * B + b) * PLANE;   // combo (0,0)
  const float* l01 = lo2 + (1 * B + b) * PLANE;   // (0,1)
  const float* l10 = lo2 + (2 * B + b) * PLANE;   // (1,0)
  const float* l11 = lo2 + (3 * B + b) * PLANE;   // (1,1)
  const int bandStride = B * PLANE;               // 3145728
  const float* h00 = highs0 + (0 * 3 * B + b) * PLANE;  // tree (0,0), band 0
  const float* h01 = highs0 + (1 * 3 * B + b) * PLANE;
  const float* h10 = highs0 + (2 * 3 * B + b) * PLANE;
  const float* h11 = highs0 + (3 * 3 * B + b) * PLANE;

  int wc3[5];
#pragma unroll
  for (int p = 0; p < 5; ++p) {
    int w = t + 2 - p;
    if (w >= WIN) w -= WIN;
    if (w < 0)  w += WIN;
    wc3[p] = w * C + c;
  }

  float la0e[5], la0o[5], la1e[5], la1o[5];
  float ha0e[5], ha0o[5], ha1e[5], ha1o[5];
#pragma unroll
  for (int k = 0; k < 5; ++k) {
    la0e[k]=0.f; la0o[k]=0.f; la1e[k]=0.f; la1o[k]=0.f;
    ha0e[k]=0.f; ha0o[k]=0.f; ha1e[k]=0.f; ha1o[k]=0.f;
  }

  const int s0 = blockIdx.y * SEG;
  float* outb = out + b * OPLANE;

#pragma unroll 1
  for (int ui = 0; ui < SEG + 4; ++ui) {
    const int u  = (s0 - 2 + ui) & (HIN - 1);
#pragma unroll
    for (int k = 0; k < 4; ++k) {
      la0e[k]=la0e[k+1]; la0o[k]=la0o[k+1]; la1e[k]=la1e[k+1]; la1o[k]=la1o[k+1];
      ha0e[k]=ha0e[k+1]; ha0o[k]=ha0o[k+1]; ha1e[k]=ha1e[k+1]; ha1o[k]=ha1o[k+1];
    }
    const int rb = u * ROWF;

    // ---- batched load pass: 80 loads, all static-indexed ----
    float rv[4][5];     // lo2 combos (0,0),(0,1),(1,0),(1,1)
    float rx[3][4][5];  // [band][tree 00,11,01,10][tap]
#pragma unroll
    for (int p = 0; p < 5; ++p) {
      const int idx = rb + wc3[p];
      rv[0][p] = l00[idx];
      rv[1][p] = l01[idx];
      rv[2][p] = l10[idx];
      rv[3][p] = l11[idx];
#pragma unroll
      for (int bb = 0; bb < 3; ++bb) {
        const int ib = idx + bb * bandStride;
        rx[bb][0][p] = h00[ib];
        rx[bb][1][p] = h11[ib];
        rx[bb][2][p] = h01[ib];
        rx[bb][3][p] = h10[ib];
      }
    }

    // ---- compute pass ----
    float A0e=0.f,A0o=0.f,A1e=0.f,A1o=0.f, H0e=0.f,H0o=0.f,H1e=0.f,H1o=0.f;
#pragma unroll
    for (int p = 0; p < 5; ++p) {
      const float a0e = c_first[0][9-2*p][0], a0o = c_first[0][8-2*p][0];
      const float b0e = c_first[0][9-2*p][1], b0o = c_first[0][8-2*p][1];
      const float a1e = c_first[1][9-2*p][0], a1o = c_first[1][8-2*p][0];
      const float b1e = c_first[1][9-2*p][1], b1o = c_first[1][8-2*p][1];
      { // lo2 terms: filter-n ch0, no butterfly
        const float v00=rv[0][p], v01=rv[1][p], v10=rv[2][p], v11=rv[3][p];
        A0e += a0e*v00 + a1e*v01;   A0o += a0o*v00 + a1o*v01;
        A1e += a0e*v10 + a1e*v11;   A1o += a0o*v10 + a1o*v11;
      }
      { // LH band (ch1 coeff)
        const float s1=(rx[0][0][p]+rx[0][1][p])*INV_SQRT2, d1=(rx[0][0][p]-rx[0][1][p])*INV_SQRT2;
        const float s2=(rx[0][2][p]+rx[0][3][p])*INV_SQRT2, d2=(rx[0][2][p]-rx[0][3][p])*INV_SQRT2;
        A0e += b0e*s1 + b1e*s2;   A0o += b0o*s1 + b1o*s2;
        A1e += b0e*d2 + b1e*d1;   A1o += b0o*d2 + b1o*d1;
      }
      { // HL band (ch0 coeff)
        const float s1=(rx[1][0][p]+rx[1][1][p])*INV_SQRT2, d1=(rx[1][0][p]-rx[1][1][p])*INV_SQRT2;
        const float s2=(rx[1][2][p]+rx[1][3][p])*INV_SQRT2, d2=(rx[1][2][p]-rx[1][3][p])*INV_SQRT2;
        H0e += a0e*s1 + a1e*s2;   H0o += a0o*s1 + a1o*s2;
        H1e += a0e*d2 + a1e*d1;   H1o += a0o*d2 + a1o*d1;
      }
      { // HH band (ch1 coeff)
        const float s1=(rx[2][0][p]+rx[2][1][p])*INV_SQRT2, d1=(rx[2][0][p]-rx[2][1][p])*INV_SQRT2;
        const float s2=(rx[2][2][p]+rx[2][3][p])*INV_SQRT2, d2=(rx[2][2][p]-rx[2][3][p])*INV_SQRT2;
        H0e += b0e*s1 + b1e*s2;   H0o += b0o*s1 + b1o*s2;
        H1e += b0e*d2 + b1e*d1;   H1o += b0o*d2 + b1o*d1;
      }
    }
    la0e[4]=A0e; la0o[4]=A0o; la1e[4]=A1e; la1o[4]=A1o;
    ha0e[4]=H0e; ha0o[4]=H0o; ha1e[4]=H1e; ha1o[4]=H1o;

    if (ui >= 4) {
      const int s = s0 + ui - 4;
      float o00=0.f, o01=0.f, o10=0.f, o11=0.f;   // o{row parity}{col parity}
#pragma unroll
      for (int p = 0; p < 5; ++p) {
        const float f00 = c_first[0][9-2*p][0], g00 = c_first[0][9-2*p][1]; // m=0, r=0
        const float f01 = c_first[0][8-2*p][0], g01 = c_first[0][8-2*p][1]; // m=0, r=1
        const float f10 = c_first[1][9-2*p][0], g10 = c_first[1][9-2*p][1]; // m=1, r=0
        const float f11 = c_first[1][8-2*p][0], g11 = c_first[1][8-2*p][1]; // m=1, r=1
        o00 += f00*la0e[4-p] + g00*ha0e[4-p] + f10*la1e[4-p] + g10*ha1e[4-p];
        o01 += f00*la0o[4-p] + g00*ha0o[4-p] + f10*la1o[4-p] + g10*ha1o[4-p];
        o10 += f01*la0e[4-p] + g01*ha0e[4-p] + f11*la1e[4-p] + g11*ha1e[4-p];
        o11 += f01*la0o[4-p] + g01*ha0o[4-p] + f11*la1o[4-p] + g11*ha1o[4-p];
      }
      float* q = outb + (2*s) * ROWO + (2*t) * C + c;
      q[0]        = o00 * 0.5f;
      q[C]        = o01 * 0.5f;
      q[ROWO]     = o10 * 0.5f;
      q[ROWO + C] = o11 * 0.5f;
    }
  }
}

extern "C" void kernel_launch(void* const* d_in, const int* in_sizes, int n_in,
                              void* d_out, int out_size, void* d_ws, size_t ws_size,
                              hipStream_t stream) {
  const float* highs0 = (const float*)d_in[0];  // (2,2,3,16,256,256,3)
  const float* highs1 = (const float*)d_in[1];  // (2,2,3,16,128,128,3)
  const float* lows   = (const float*)d_in[2];  // (2,2,16,128,128,3)
  float* out = (float*)d_out;                   // (16,512,512,3)
  float* lo2 = (float*)d_ws;                    // 4*16*256*256*3 floats = 50.3 MB

  // Stage 1: 384 cols/plane -> 3 blocks of 128; 8 row segments of 16; 4x16 planes
  dim3 b1(128), g1(3, 8, 64);
  hipLaunchKernelGGL(idtcwt_stage1, g1, b1, 0, stream, lows, highs1, lo2);

  // Stage 2: 768 cols -> 3 blocks of 256; 16 row segments of 16; 16 batches
  dim3 b2(256), g2(3, 16, 16);
  hipLaunchKernelGGL(idtcwt_stage2, g2, b2, 0, stream, lo2, highs0, out);
}